// Round 9
// baseline (156.651 us; speedup 1.0000x reference)
//
#include <hip/hip_runtime.h>
#include <stdint.h>

#define B_    2
#define N_    2048
#define DIM_  1024
#define H_    16
#define DH_   64
#define NR_   4096     // B*N rows
#define NQKV_ 3072
#define NQK_  2048     // q,k columns kept in qkv2

typedef unsigned short u16;
typedef __attribute__((ext_vector_type(8))) short short8;
typedef __attribute__((ext_vector_type(4))) float f32x4;

static __device__ __forceinline__ u16 f2bf(float f){
  union { float f; uint32_t u; } x; x.f = f;
  return (u16)((x.u + 0x7fffu + ((x.u >> 16) & 1u)) >> 16);
}
static __device__ __forceinline__ float bf2f(uint32_t b){
  union { uint32_t u; float f; } x; x.u = b << 16;
  return x.f;
}
// hardware packed f32->bf16 (RNE): D = {lo: bf16(a), hi: bf16(b)}
static __device__ __forceinline__ uint32_t cvtpk(float a, float b){
  uint32_t r;
  asm("v_cvt_pk_bf16_f32 %0, %1, %2" : "=v"(r) : "v"(a), "v"(b));
  return r;
}

// global -> LDS direct copy, 16B per lane; LDS dest is wave-uniform base + lane*16
#define GLL16(gp, lp) __builtin_amdgcn_global_load_lds( \
    (const __attribute__((address_space(1))) void*)(gp), \
    (__attribute__((address_space(3))) void*)(lp), 16, 0, 0)

#define SCHEDB __builtin_amdgcn_sched_barrier(0)
#define BARRIER __builtin_amdgcn_s_barrier()

// ---------------- RMSNorm + cast to bf16 ----------------
__global__ __launch_bounds__(256) void k_rmsnorm(const float* __restrict__ x,
                                                 const float* __restrict__ w,
                                                 u16* __restrict__ xn){
  int row = blockIdx.x;
  int t = threadIdx.x;
  float4 v = ((const float4*)(x + (size_t)row * DIM_))[t];
  float ss = v.x*v.x + v.y*v.y + v.z*v.z + v.w*v.w;
#pragma unroll
  for (int m = 1; m < 64; m <<= 1) ss += __shfl_xor(ss, m, 64);
  __shared__ float red[4];
  if ((t & 63) == 0) red[t >> 6] = ss;
  __syncthreads();
  float tot = red[0] + red[1] + red[2] + red[3];
  float r = rsqrtf(tot * (1.0f / DIM_) + 1.1920929e-07f);
  float4 wv = ((const float4*)w)[t];
  union { u16 u[4]; uint2 v2; } o;
  o.u[0] = f2bf(v.x * r * wv.x);
  o.u[1] = f2bf(v.y * r * wv.y);
  o.u[2] = f2bf(v.z * r * wv.z);
  o.u[3] = f2bf(v.w * r * wv.w);
  ((uint2*)(xn + (size_t)row * DIM_))[t] = o.v2;
}

// ---------------- fp32 [R][C] -> bf16 [C][R] transpose-cast ----------------
__global__ __launch_bounds__(256) void k_tcast(const float* __restrict__ src,
                                               u16* __restrict__ dst, int R, int C){
  __shared__ float ls[64][65];
  int c0 = blockIdx.x * 64, r0 = blockIdx.y * 64;
  int t = threadIdx.x;
  int rr = t >> 2, q = t & 3;
  const float* s = src + (size_t)(r0 + rr) * C + c0 + q * 16;
#pragma unroll
  for (int j = 0; j < 4; j++){
    float4 v = ((const float4*)s)[j];
    ls[rr][q*16 + j*4 + 0] = v.x;
    ls[rr][q*16 + j*4 + 1] = v.y;
    ls[rr][q*16 + j*4 + 2] = v.z;
    ls[rr][q*16 + j*4 + 3] = v.w;
  }
  __syncthreads();
  int cc = t >> 2;
  union { u16 u[16]; uint4 v4[2]; } o;
#pragma unroll
  for (int i = 0; i < 16; i++) o.u[i] = f2bf(ls[q*16 + i][cc]);
  u16* d = dst + (size_t)(c0 + cc) * R + r0 + q * 16;
  ((uint4*)d)[0] = o.v4[0];
  ((uint4*)d)[1] = o.v4[1];
}

// ---------------- cos/sin table [N][32] ----------------
__global__ void k_cs(float2* __restrict__ cs){
  int tid = blockIdx.x * blockDim.x + threadIdx.x;
  if (tid >= N_ * 32) return;
  int n = tid >> 5, i = tid & 31;
  float inv = powf(10000.0f, -(float)(2 * i) * (1.0f / 64.0f));
  float a = (float)n * inv;
  cs[tid] = make_float2(cosf(a), sinf(a));
}

// ---------------- RoPE in-place on q|k of qkv2; q also scaled by 1/8 ----------------
__global__ __launch_bounds__(256) void k_rope(u16* __restrict__ qkv2,
                                              const float2* __restrict__ cs){
  int tid = blockIdx.x * 256 + threadIdx.x;   // 1,048,576 threads, 8 elems each
  int row = tid >> 8;
  int cid = (tid & 255) << 3;                 // 0..2040 (q:0..1023, k:1024..2047)
  int n = row & (N_ - 1);
  int i0 = (cid & 63) >> 1;
  float sc = (cid < DIM_) ? 0.125f : 1.0f;
  u16* p = qkv2 + (size_t)row * NQK_ + cid;
  uint4 v = *(const uint4*)p;
  uint32_t w[4] = {v.x, v.y, v.z, v.w};
  const float4* cp = (const float4*)(cs + (size_t)n * 32 + i0);
  float4 c01 = cp[0], c23 = cp[1];
  float cj[4] = {c01.x, c01.z, c23.x, c23.z};
  float sj[4] = {c01.y, c01.w, c23.y, c23.w};
#pragma unroll
  for (int jj = 0; jj < 4; jj++){
    float x0 = bf2f(w[jj] & 0xffffu), x1 = bf2f(w[jj] >> 16);
    float y0 = (x0 * cj[jj] - x1 * sj[jj]) * sc;
    float y1 = (x1 * cj[jj] + x0 * sj[jj]) * sc;
    w[jj] = cvtpk(y0, y1);
  }
  uint4 ov = {w[0], w[1], w[2], w[3]};
  *(uint4*)p = ov;
}

// ---------------- GEMM1: 256x256 tile, 8-phase interleave, counted vmcnt ----------------
// C[4096,3072] = xn @ wqkvT^T. 512 thr = 8 waves (2M x 4N), per-wave 128x64 out.
// LDS k-half-split: [buf][khalf][256 rows][32 k], 16KB halves, 128KB total.
// Per K-tile: 4 phases; phase p = {mi-half p&1, khalf p>>1}: 4-8 ds_read_b128 +
// 1 half-tile prefetch (2 gload_lds) + barrier + lgkmcnt(0) + 16 MFMA + barrier.
// vmcnt(4) only at phases 1,3 (2 half-tiles allowed in flight; 0 only at tail).
// Grid 192 = 16m x 12n; XCD 2D chunk 4m x 6n.
__global__ __launch_bounds__(512, 2) void k_gemm1(const u16* __restrict__ A,
                                                  const u16* __restrict__ Bt,
                                                  u16* __restrict__ outb,
                                                  float* __restrict__ outf,
                                                  u16* __restrict__ vt2){
  __shared__ u16 As[2][2][8192];   // [buf][kh][256r x 32k], chunk-swizzled (64KB)
  __shared__ u16 Bs[2][2][8192];   // (64KB)
  const int K = 1024, KT = 16;

  int xcd = blockIdx.x & 7, c = blockIdx.x >> 3;       // c in 0..23
  int m0 = ((xcd >> 1) * 4 + c / 6) << 8;              // m-panel 0..15
  int n0 = ((xcd & 1) * 6 + c % 6) << 8;               // n-panel 0..11

  int t = threadIdx.x, wv = t >> 6, lane = t & 63, l15 = lane & 15, g = lane >> 4;
  int wm = wv >> 2, wn = wv & 3;                       // 2 x 4 wave grid

  const u16* Ap = A + (size_t)m0 * K;
  const u16* Bp = Bt + (size_t)n0 * K;

  // stage one k-half (16KB = 256 rows x 32 k) of K-tile kt: 2 gload_lds per wave.
  // slot s = (issue*8+wv)*64+lane; row = s>>2; phys chunk = s&3;
  // logical chunk = phys ^ ((row>>1)&3)  [involution; read side uses the same]
  auto STG = [&](u16* lds, const u16* gsrc, int kt, int kh){
#pragma unroll
    for (int i = 0; i < 2; i++){
      int s = (i * 8 + wv) * 64 + lane;
      int row = s >> 2;
      int cc = (s & 3) ^ ((row >> 1) & 3);
      GLL16(gsrc + (size_t)row * K + kt * 64 + kh * 32 + cc * 8, lds + (i * 8 + wv) * 512);
    }
  };

  f32x4 acc[8][4] = {};

  // prologue: K-tile 0 fully staged; wait its kh0 (allow kh1 in flight)
  STG(&As[0][0][0], Ap, 0, 0);
  STG(&Bs[0][0][0], Bp, 0, 0);
  STG(&As[0][1][0], Ap, 0, 1);
  STG(&Bs[0][1][0], Bp, 0, 1);
  asm volatile("s_waitcnt vmcnt(4)" ::: "memory");
  SCHEDB; BARRIER; SCHEDB;

  for (int kt = 0; kt < KT; kt++){
    int buf = kt & 1, nbuf = buf ^ 1;
    bool pre = (kt + 1 < KT);
    short8 bfrag[4];
#pragma unroll
    for (int p = 0; p < 4; p++){
      const int kk = p >> 1;
      const int mib = (p & 1) ? 4 : 0;
      // ds_read fragments (data guaranteed by previous phase-end vmcnt+barrier)
      if (!(p & 1)){
#pragma unroll
        for (int ni = 0; ni < 4; ni++){
          int rr = wn * 64 + ni * 16 + l15;
          bfrag[ni] = *(const short8*)(&Bs[buf][kk][rr * 32 + ((g ^ ((rr >> 1) & 3)) << 3)]);
        }
      }
      short8 afrag[4];
#pragma unroll
      for (int mi = 0; mi < 4; mi++){
        int rr = wm * 128 + (mib + mi) * 16 + l15;
        afrag[mi] = *(const short8*)(&As[buf][kk][rr * 32 + ((g ^ ((rr >> 1) & 3)) << 3)]);
      }
      // prefetch one half-tile of K-tile kt+1: p0:Ah0 p1:Bh0 p2:Ah1 p3:Bh1
      if (pre){
        if (p == 0)      STG(&As[nbuf][0][0], Ap, kt + 1, 0);
        else if (p == 1) STG(&Bs[nbuf][0][0], Bp, kt + 1, 0);
        else if (p == 2) STG(&As[nbuf][1][0], Ap, kt + 1, 1);
        else             STG(&Bs[nbuf][1][0], Bp, kt + 1, 1);
      }
      SCHEDB; BARRIER;
      asm volatile("s_waitcnt lgkmcnt(0)" ::: "memory");
      SCHEDB;
      __builtin_amdgcn_s_setprio(1);
#pragma unroll
      for (int mi = 0; mi < 4; mi++)
#pragma unroll
        for (int ni = 0; ni < 4; ni++)
          acc[mib + mi][ni] = __builtin_amdgcn_mfma_f32_16x16x32_bf16(afrag[mi], bfrag[ni], acc[mib + mi][ni], 0, 0, 0);
      __builtin_amdgcn_s_setprio(0);
      // counted waits: before next phase's kh1 reads (p1) / next K-tile's kh0 reads (p3)
      if (p == 1){
        if (pre) asm volatile("s_waitcnt vmcnt(4)" ::: "memory");
        else     asm volatile("s_waitcnt vmcnt(0)" ::: "memory");
      }
      if (p == 3 && pre) asm volatile("s_waitcnt vmcnt(4)" ::: "memory");
      SCHEDB; BARRIER; SCHEDB;
    }
  }

#pragma unroll
  for (int mi = 0; mi < 8; mi++){
#pragma unroll
    for (int ni = 0; ni < 4; ni++){
      int col = n0 + wn * 64 + ni * 16 + l15;
#pragma unroll
      for (int r = 0; r < 4; r++){
        int row = m0 + wm * 128 + mi * 16 + g * 4 + r;
        float val = acc[mi][ni][r];
        if (col < NQK_){
          outb[(size_t)row * NQK_ + col] = f2bf(val);
        } else {
          int hh = (col - 2 * DIM_) >> 6, d = col & 63;
          int b = row >> 11, n = row & (N_ - 1);
          outf[((size_t)((b * H_ + hh) * N_ + n) << 6) + d] = val;
          // vT2 tiled: [bh][n>>5][d][n&31]
          vt2[((size_t)((b * H_ + hh) * 64 + (n >> 5)) * 64 + d) * 32 + (n & 31)] = f2bf(val);
        }
      }
    }
  }
}

// ---------------- GEMM2: 128x128 tile, BK=64, counted-vmcnt schedule ----------------
// out0[M=4096, N=1024] fp32 = ao[4096,1024] @ woutT[1024,1024]^T
// Grid 256 = 32m x 8n; per-XCD chunk = 4 m-panels x all n (A 1MB + B 2MB, L2-fit).
__global__ __launch_bounds__(256, 2) void k_gemm2(const u16* __restrict__ A,
                                                  const u16* __restrict__ Bt,
                                                  float* __restrict__ outf){
  __shared__ u16 As[2][8192];
  __shared__ u16 Bs[2][8192];
  const int K = 1024, KT = 16, N = 1024;

  int xcd = blockIdx.x & 7, c = blockIdx.x >> 3;       // c in 0..31
  int m0 = (xcd * 4 + (c >> 3)) << 7;
  int n0 = (c & 7) << 7;

  int t = threadIdx.x, wv = t >> 6, lane = t & 63, l15 = lane & 15, g = lane >> 4;
  int wm = wv >> 1, wn = wv & 1;

  auto STAGE = [&](int buf, int kt){
    int k0 = kt << 6;
#pragma unroll
    for (int i = 0; i < 4; i++){
      int cc = (i * 4 + wv) * 64 + lane;
      int m = cc >> 3, pos = cc & 7;
      GLL16(A + (size_t)(m0 + m) * K + k0 + ((pos ^ (m & 7)) << 3), &As[buf][(i * 4 + wv) * 512]);
    }
#pragma unroll
    for (int i = 0; i < 4; i++){
      int cc = (i * 4 + wv) * 64 + lane;
      int n = cc >> 3, pos = cc & 7;
      GLL16(Bt + (size_t)(n0 + n) * K + k0 + ((pos ^ (n & 7)) << 3), &Bs[buf][(i * 4 + wv) * 512]);
    }
  };

  f32x4 acc[4][4] = {};
  STAGE(0, 0);
  STAGE(1, 1);

  for (int kt = 0; kt < KT; kt++){
    if (kt < KT - 1) asm volatile("s_waitcnt vmcnt(8)" ::: "memory");
    else             asm volatile("s_waitcnt vmcnt(0)" ::: "memory");
    SCHEDB; BARRIER; SCHEDB;
    const u16* Asc = &As[kt & 1][0];
    const u16* Bsc = &Bs[kt & 1][0];
#pragma unroll
    for (int h = 0; h < 2; h++){
      short8 af[4], bfr[4];
#pragma unroll
      for (int mi = 0; mi < 4; mi++){
        int m = wm * 64 + mi * 16 + l15;
        af[mi] = *(const short8*)(Asc + m * 64 + (((h * 4 + g) ^ (m & 7)) << 3));
      }
#pragma unroll
      for (int ni = 0; ni < 4; ni++){
        int n = wn * 64 + ni * 16 + l15;
        bfr[ni] = *(const short8*)(Bsc + n * 64 + (((h * 4 + g) ^ (n & 7)) << 3));
      }
      __builtin_amdgcn_s_setprio(1);
#pragma unroll
      for (int mi = 0; mi < 4; mi++)
#pragma unroll
        for (int ni = 0; ni < 4; ni++)
          acc[mi][ni] = __builtin_amdgcn_mfma_f32_16x16x32_bf16(af[mi], bfr[ni], acc[mi][ni], 0, 0, 0);
      __builtin_amdgcn_s_setprio(0);
    }
    asm volatile("s_waitcnt lgkmcnt(0)" ::: "memory");
    SCHEDB; BARRIER; SCHEDB;
    if (kt + 2 < KT) STAGE(kt & 1, kt + 2);
  }

#pragma unroll
  for (int mi = 0; mi < 4; mi++){
#pragma unroll
    for (int ni = 0; ni < 4; ni++){
      int col = n0 + wn * 64 + ni * 16 + l15;
#pragma unroll
      for (int r = 0; r < 4; r++){
        int row = m0 + wm * 64 + mi * 16 + g * 4 + r;
        outf[(size_t)row * N + col] = acc[mi][ni][r];
      }
    }
  }
}

// ---------------- flash block-causal attention (unchanged from R8) ----------------
__global__ __launch_bounds__(512, 4) void k_attn(const u16* __restrict__ qkv2,
                                                 const u16* __restrict__ vt2,
                                                 u16* __restrict__ ao){
  __shared__ u16 Ks[2][8192];   // [kv=128][hd=64] per buf, XOR-swizzled chunks (32KB)
  __shared__ u16 Vs[8192];      // [d=64][kv=128], XOR-swizzled chunks (16KB)
  __shared__ u16 Ps[8][1024];   // per-wave P half [16q][64kv], swizzle ^((q&7)<<4) (16KB)

  int bid = blockIdx.x;
  int bh = bid & 31;                          // bid%8 stable -> same-bh on same XCD
  int idx = (bid >> 5) & 7;
  int half = bid >> 8;
  int qb = half ? idx : 15 - idx;
  int b = bh >> 4, h = bh & 15;
  int t = threadIdx.x, wv = t >> 6, lane = t & 63, l15 = lane & 15, g = lane >> 4;

  int qrow = qb * 128 + wv * 16 + l15;
  const u16* qp = qkv2 + (size_t)(b * N_ + qrow) * NQK_ + h * 64 + g * 8;
  short8 qfa = *(const short8*)qp;        // already roped + 1/8-scaled
  short8 qfb = *(const short8*)(qp + 32);

  char* Pw = (char*)&Ps[wv][0];
  const u16* vb_ = vt2 + (size_t)bh * 4096 * 32;   // vt2[bh][nc][d][32]

  auto STAGE_K = [&](int buf, int j) {
#pragma unroll
    for (int i = 0; i < 2; i++){
      int c = (i * 8 + wv) * 64 + lane;
      int kv = c >> 3, pos = c & 7;
      GLL16(qkv2 + (size_t)(b * N_ + j * 128 + kv) * NQK_ + DIM_ + h * 64 + ((pos ^ (kv & 7)) << 3),
            &Ks[buf][(i * 8 + wv) * 512]);
    }
  };
  auto STAGE_V = [&](int j) {
#pragma unroll
    for (int i = 0; i < 2; i++){
      int c = (wv * 2 + i) * 64 + lane;
      int d = c >> 4;
      int lc = (c & 15) ^ (d & 7);
      GLL16(vb_ + ((size_t)((j * 4 + (lc >> 2)) * 64 + d) * 32) + ((lc & 3) << 3),
            &Vs[(wv * 2 + i) * 512]);
    }
  };

  f32x4 oacc[4] = {};
  float m_run = -INFINITY, l_run = 0.0f;

  STAGE_K(0, 0);
  __syncthreads();
  int cur = 0;

  for (int j = 0; j <= qb; j++){
    STAGE_V(j);                                // issues 2 loads (oldest)
    if (j < qb) STAGE_K(cur ^ 1, j + 1);       // issues 2 more (newest)
    const u16* K = &Ks[cur][0];

    f32x4 sv[8];
    __builtin_amdgcn_s_setprio(1);
#pragma unroll
    for (int s = 0; s < 8; s++){
      int kvr = s * 16 + l15;
      short8 kf0 = *(const short8*)(K + kvr * 64 + ((g ^ (kvr & 7)) << 3));
      short8 kf1 = *(const short8*)(K + kvr * 64 + (((4 + g) ^ (kvr & 7)) << 3));
      f32x4 z = {0.f, 0.f, 0.f, 0.f};
      z = __builtin_amdgcn_mfma_f32_16x16x32_bf16(kf0, qfa, z, 0, 0, 0);
      z = __builtin_amdgcn_mfma_f32_16x16x32_bf16(kf1, qfb, z, 0, 0, 0);
      sv[s] = z;
    }
    __builtin_amdgcn_s_setprio(0);

    float mt = -INFINITY;
#pragma unroll
    for (int s = 0; s < 8; s++)
#pragma unroll
      for (int r = 0; r < 4; r++) mt = fmaxf(mt, sv[s][r]);
    mt = fmaxf(mt, __shfl_xor(mt, 16, 64));
    mt = fmaxf(mt, __shfl_xor(mt, 32, 64));
    if (!__all(mt <= m_run + 8.0f)){
      float m_new = fmaxf(m_run, mt);
      float alpha = exp2f((m_run - m_new) * 1.44269504f);
      float af4[4];
#pragma unroll
      for (int r = 0; r < 4; r++) af4[r] = __shfl(alpha, g * 4 + r, 64);
#pragma unroll
      for (int ni = 0; ni < 4; ni++)
#pragma unroll
        for (int r = 0; r < 4; r++) oacc[ni][r] *= af4[r];
      l_run *= alpha;
      m_run = m_new;
    }
    float psum = 0.0f;
#pragma unroll
    for (int s = 0; s < 8; s++)
#pragma unroll
      for (int r = 0; r < 4; r++){
        float p = exp2f((sv[s][r] - m_run) * 1.44269504f);
        sv[s][r] = p;
        psum += p;
      }
    psum += __shfl_xor(psum, 16, 64);
    psum += __shfl_xor(psum, 32, 64);
    l_run += psum;

    // V(j) landed (own oldest 2 loads); K(j+1) stays in flight through PV
    if (j < qb) asm volatile("s_waitcnt vmcnt(2)" ::: "memory");
    else        asm volatile("s_waitcnt vmcnt(0)" ::: "memory");
    SCHEDB; BARRIER; SCHEDB;

#pragma unroll
    for (int hf = 0; hf < 2; hf++){
#pragma unroll
      for (int s2 = 0; s2 < 4; s2++){
        int s = hf * 4 + s2;
        uint2 pk;
        pk.x = cvtpk(sv[s][0], sv[s][1]);
        pk.y = cvtpk(sv[s][2], sv[s][3]);
        int byte = (l15 * 128 + s2 * 32 + g * 8) ^ ((l15 & 7) << 4);
        *(uint2*)(Pw + byte) = pk;
      }
      __builtin_amdgcn_s_setprio(1);
#pragma unroll
      for (int cc2 = 0; cc2 < 2; cc2++){
        int cc = hf * 2 + cc2;
        int rb = (l15 * 128 + cc2 * 64 + g * 16) ^ ((l15 & 7) << 4);
        short8 pa = *(const short8*)(Pw + rb);
#pragma unroll
        for (int ni = 0; ni < 4; ni++){
          int d = ni * 16 + l15;
          short8 vf = *(const short8*)(Vs + d * 128 + (((cc * 4 + g) ^ (d & 7)) << 3));
          oacc[ni] = __builtin_amdgcn_mfma_f32_16x16x32_bf16(pa, vf, oacc[ni], 0, 0, 0);
        }
      }
      __builtin_amdgcn_s_setprio(0);
    }

    __syncthreads();   // all waves done with Vs / Ks[cur]; K(j+1) drained (flew full tile)
    cur ^= 1;
  }

  float lf[4];
#pragma unroll
  for (int r = 0; r < 4; r++) lf[r] = 1.0f / __shfl(l_run, g * 4 + r, 64);
#pragma unroll
  for (int ni = 0; ni < 4; ni++)
#pragma unroll
    for (int r = 0; r < 4; r++){
      size_t idxo = (size_t)(b * N_ + qb * 128 + wv * 16 + g * 4 + r) * DIM_ + h * 64 + ni * 16 + l15;
      ao[idxo] = f2bf(oacc[ni][r] * lf[r]);
    }
}

// ---------------- launch ----------------
extern "C" void kernel_launch(void* const* d_in, const int* in_sizes, int n_in,
                              void* d_out, int out_size, void* d_ws, size_t ws_size,
                              hipStream_t stream){
  const float* x      = (const float*)d_in[0];
  const float* norm_w = (const float*)d_in[1];
  const float* w_qkv  = (const float*)d_in[2];
  const float* w_out  = (const float*)d_in[3];
  float* out0 = (float*)d_out;                      // [B,N,DIM] fp32
  float* out1 = out0 + (size_t)NR_ * DIM_;          // orig_v [B,H,N,DH] fp32

  char* ws = (char*)d_ws;
  u16* xn    = (u16*)(ws + 0);           // 8 MB (reused as attn-out after GEMM1)
  u16* wqkvT = (u16*)(ws + 8388608);     // 6 MB
  u16* woutT = (u16*)(ws + 14680064);    // 2 MB
  u16* qkv2  = (u16*)(ws + 16777216);    // 16 MB  [row][2048] q|k bf16
  u16* vt2   = (u16*)(ws + 33554432);    // 8 MB   [bh][64][64][32] bf16
  float2* cs = (float2*)(ws + 41943040); // 0.5 MB
  u16* ao    = xn;                       // alias: xn dead after GEMM1

  k_rmsnorm<<<NR_, 256, 0, stream>>>(x, norm_w, xn);
  k_tcast<<<dim3(NQKV_ / 64, DIM_ / 64), 256, 0, stream>>>(w_qkv, wqkvT, DIM_, NQKV_);
  k_tcast<<<dim3(DIM_ / 64, DIM_ / 64), 256, 0, stream>>>(w_out, woutT, DIM_, DIM_);
  k_cs<<<(N_ * 32) / 256, 256, 0, stream>>>(cs);
  k_gemm1<<<192, 512, 0, stream>>>(xn, wqkvT, qkv2, out1, vt2);
  k_rope<<<4096, 256, 0, stream>>>(qkv2, cs);
  k_attn<<<512, 512, 0, stream>>>(qkv2, vt2, ao);
  k_gemm2<<<256, 256, 0, stream>>>(ao, woutT, out0);
}

// Round 10
// 136.062 us; speedup vs baseline: 1.1513x; 1.1513x over previous
//
#include <hip/hip_runtime.h>
#include <stdint.h>

#define B_    2
#define N_    2048
#define DIM_  1024
#define H_    16
#define DH_   64
#define NR_   4096     // B*N rows
#define NQKV_ 3072
#define NQK_  2048     // q,k columns kept in qkv2

typedef unsigned short u16;
typedef __attribute__((ext_vector_type(8))) short short8;
typedef __attribute__((ext_vector_type(4))) float f32x4;

static __device__ __forceinline__ u16 f2bf(float f){
  union { float f; uint32_t u; } x; x.f = f;
  return (u16)((x.u + 0x7fffu + ((x.u >> 16) & 1u)) >> 16);
}
static __device__ __forceinline__ float bf2f(uint32_t b){
  union { uint32_t u; float f; } x; x.u = b << 16;
  return x.f;
}
// hardware packed f32->bf16 (RNE): D = {lo: bf16(a), hi: bf16(b)}
static __device__ __forceinline__ uint32_t cvtpk(float a, float b){
  uint32_t r;
  asm("v_cvt_pk_bf16_f32 %0, %1, %2" : "=v"(r) : "v"(a), "v"(b));
  return r;
}

// global -> LDS direct copy, 16B per lane; LDS dest is wave-uniform base + lane*16
#define GLL16(gp, lp) __builtin_amdgcn_global_load_lds( \
    (const __attribute__((address_space(1))) void*)(gp), \
    (__attribute__((address_space(3))) void*)(lp), 16, 0, 0)

#define SCHEDB __builtin_amdgcn_sched_barrier(0)
#define BARRIER __builtin_amdgcn_s_barrier()

// ---------------- RMSNorm + cast to bf16 ----------------
__global__ __launch_bounds__(256) void k_rmsnorm(const float* __restrict__ x,
                                                 const float* __restrict__ w,
                                                 u16* __restrict__ xn){
  int row = blockIdx.x;
  int t = threadIdx.x;
  float4 v = ((const float4*)(x + (size_t)row * DIM_))[t];
  float ss = v.x*v.x + v.y*v.y + v.z*v.z + v.w*v.w;
#pragma unroll
  for (int m = 1; m < 64; m <<= 1) ss += __shfl_xor(ss, m, 64);
  __shared__ float red[4];
  if ((t & 63) == 0) red[t >> 6] = ss;
  __syncthreads();
  float tot = red[0] + red[1] + red[2] + red[3];
  float r = rsqrtf(tot * (1.0f / DIM_) + 1.1920929e-07f);
  float4 wv = ((const float4*)w)[t];
  union { u16 u[4]; uint2 v2; } o;
  o.u[0] = f2bf(v.x * r * wv.x);
  o.u[1] = f2bf(v.y * r * wv.y);
  o.u[2] = f2bf(v.z * r * wv.z);
  o.u[3] = f2bf(v.w * r * wv.w);
  ((uint2*)(xn + (size_t)row * DIM_))[t] = o.v2;
}

// ---------------- fp32 [R][C] -> bf16 [C][R] transpose-cast ----------------
__global__ __launch_bounds__(256) void k_tcast(const float* __restrict__ src,
                                               u16* __restrict__ dst, int R, int C){
  __shared__ float ls[64][65];
  int c0 = blockIdx.x * 64, r0 = blockIdx.y * 64;
  int t = threadIdx.x;
  int rr = t >> 2, q = t & 3;
  const float* s = src + (size_t)(r0 + rr) * C + c0 + q * 16;
#pragma unroll
  for (int j = 0; j < 4; j++){
    float4 v = ((const float4*)s)[j];
    ls[rr][q*16 + j*4 + 0] = v.x;
    ls[rr][q*16 + j*4 + 1] = v.y;
    ls[rr][q*16 + j*4 + 2] = v.z;
    ls[rr][q*16 + j*4 + 3] = v.w;
  }
  __syncthreads();
  int cc = t >> 2;
  union { u16 u[16]; uint4 v4[2]; } o;
#pragma unroll
  for (int i = 0; i < 16; i++) o.u[i] = f2bf(ls[q*16 + i][cc]);
  u16* d = dst + (size_t)(c0 + cc) * R + r0 + q * 16;
  ((uint4*)d)[0] = o.v4[0];
  ((uint4*)d)[1] = o.v4[1];
}

// ---------------- cos/sin table [N][32] ----------------
__global__ void k_cs(float2* __restrict__ cs){
  int tid = blockIdx.x * blockDim.x + threadIdx.x;
  if (tid >= N_ * 32) return;
  int n = tid >> 5, i = tid & 31;
  float inv = powf(10000.0f, -(float)(2 * i) * (1.0f / 64.0f));
  float a = (float)n * inv;
  cs[tid] = make_float2(cosf(a), sinf(a));
}

// ---------------- RoPE in-place on q|k of qkv2; q also scaled by 1/8 ----------------
__global__ __launch_bounds__(256) void k_rope(u16* __restrict__ qkv2,
                                              const float2* __restrict__ cs){
  int tid = blockIdx.x * 256 + threadIdx.x;   // 1,048,576 threads, 8 elems each
  int row = tid >> 8;
  int cid = (tid & 255) << 3;                 // 0..2040 (q:0..1023, k:1024..2047)
  int n = row & (N_ - 1);
  int i0 = (cid & 63) >> 1;
  float sc = (cid < DIM_) ? 0.125f : 1.0f;
  u16* p = qkv2 + (size_t)row * NQK_ + cid;
  uint4 v = *(const uint4*)p;
  uint32_t w[4] = {v.x, v.y, v.z, v.w};
  const float4* cp = (const float4*)(cs + (size_t)n * 32 + i0);
  float4 c01 = cp[0], c23 = cp[1];
  float cj[4] = {c01.x, c01.z, c23.x, c23.z};
  float sj[4] = {c01.y, c01.w, c23.y, c23.w};
#pragma unroll
  for (int jj = 0; jj < 4; jj++){
    float x0 = bf2f(w[jj] & 0xffffu), x1 = bf2f(w[jj] >> 16);
    float y0 = (x0 * cj[jj] - x1 * sj[jj]) * sc;
    float y1 = (x1 * cj[jj] + x0 * sj[jj]) * sc;
    w[jj] = cvtpk(y0, y1);
  }
  uint4 ov = {w[0], w[1], w[2], w[3]};
  *(uint4*)p = ov;
}

// ---------------- GEMM1: 128x192 tile, BK=64, counted-vmcnt, grid 512 ----------------
// C[4096,3072] = xn @ wqkvT^T. 256 thr = 4 waves (2m x 2n), per-wave 64 x 96 out.
// Grid 512 = 32m x 16n = EXACTLY one generation at 2 blocks/CU (80KB LDS).
// XCD 2D chunk: 8 m-panels x 8 n-panels per XCD (A 2MB + B 3MB).
// cols<2048 -> bf16 qkv2 (un-roped); cols>=2048 -> fp32 orig_v + bf16 vT2 tiled.
__global__ __launch_bounds__(256, 2) void k_gemm1(const u16* __restrict__ A,
                                                  const u16* __restrict__ Bt,
                                                  u16* __restrict__ outb,
                                                  float* __restrict__ outf,
                                                  u16* __restrict__ vt2){
  __shared__ u16 As[2][8192];    // [128 m][64 k] per buf, chunk-XOR swizzle (32KB)
  __shared__ u16 Bs[2][12288];   // [192 n][64 k] per buf (48KB)
  const int K = 1024, KT = 16;

  int xcd = blockIdx.x & 7, c = blockIdx.x >> 3;       // c in 0..63
  int m0 = ((xcd >> 1) * 8 + (c >> 3)) << 7;           // m-panel 0..31 (128 rows)
  int n0 = ((xcd & 1) * 8 + (c & 7)) * 192;            // n-panel 0..15 (192 cols)

  int t = threadIdx.x, wv = t >> 6, lane = t & 63, l15 = lane & 15, g = lane >> 4;
  int wm = wv >> 1, wn = wv & 1;

  auto STAGE = [&](int buf, int kt){
    int k0 = kt << 6;
#pragma unroll
    for (int i = 0; i < 4; i++){           // A: 128 rows x 64 k = 16KB
      int cc = (i * 4 + wv) * 64 + lane;
      int m = cc >> 3, pos = cc & 7;
      GLL16(A + (size_t)(m0 + m) * K + k0 + ((pos ^ (m & 7)) << 3), &As[buf][(i * 4 + wv) * 512]);
    }
#pragma unroll
    for (int i = 0; i < 6; i++){           // B: 192 rows x 64 k = 24KB
      int cc = (i * 4 + wv) * 64 + lane;
      int n = cc >> 3, pos = cc & 7;
      GLL16(Bt + (size_t)(n0 + n) * K + k0 + ((pos ^ (n & 7)) << 3), &Bs[buf][(i * 4 + wv) * 512]);
    }
  };

  f32x4 acc[4][6] = {};
  STAGE(0, 0);
  STAGE(1, 1);

  for (int kt = 0; kt < KT; kt++){
    // wait own 10 loads of tile kt; tile kt+1 (10 more) stays in flight
    if (kt < KT - 1) asm volatile("s_waitcnt vmcnt(10)" ::: "memory");
    else             asm volatile("s_waitcnt vmcnt(0)" ::: "memory");
    SCHEDB; BARRIER; SCHEDB;
    const u16* Asc = &As[kt & 1][0];
    const u16* Bsc = &Bs[kt & 1][0];
#pragma unroll
    for (int h = 0; h < 2; h++){
      short8 af[4], bfr[6];
#pragma unroll
      for (int mi = 0; mi < 4; mi++){
        int m = wm * 64 + mi * 16 + l15;
        af[mi] = *(const short8*)(Asc + m * 64 + (((h * 4 + g) ^ (m & 7)) << 3));
      }
#pragma unroll
      for (int ni = 0; ni < 6; ni++){
        int n = wn * 96 + ni * 16 + l15;
        bfr[ni] = *(const short8*)(Bsc + n * 64 + (((h * 4 + g) ^ (n & 7)) << 3));
      }
      __builtin_amdgcn_s_setprio(1);
#pragma unroll
      for (int mi = 0; mi < 4; mi++)
#pragma unroll
        for (int ni = 0; ni < 6; ni++)
          acc[mi][ni] = __builtin_amdgcn_mfma_f32_16x16x32_bf16(af[mi], bfr[ni], acc[mi][ni], 0, 0, 0);
      __builtin_amdgcn_s_setprio(0);
    }
    asm volatile("s_waitcnt lgkmcnt(0)" ::: "memory");
    SCHEDB; BARRIER; SCHEDB;                           // all waves done reading buf[kt&1]
    if (kt + 2 < KT) STAGE(kt & 1, kt + 2);            // refill freed buffer; 2 K-steps to fly
  }

#pragma unroll
  for (int mi = 0; mi < 4; mi++){
#pragma unroll
    for (int ni = 0; ni < 6; ni++){
      int col = n0 + wn * 96 + ni * 16 + l15;
#pragma unroll
      for (int r = 0; r < 4; r++){
        int row = m0 + wm * 64 + mi * 16 + g * 4 + r;
        float val = acc[mi][ni][r];
        if (col < NQK_){
          outb[(size_t)row * NQK_ + col] = f2bf(val);
        } else {
          int hh = (col - 2 * DIM_) >> 6, d = col & 63;
          int b = row >> 11, n = row & (N_ - 1);
          outf[((size_t)((b * H_ + hh) * N_ + n) << 6) + d] = val;
          // vT2 tiled: [bh][n>>5][d][n&31]
          vt2[((size_t)((b * H_ + hh) * 64 + (n >> 5)) * 64 + d) * 32 + (n & 31)] = f2bf(val);
        }
      }
    }
  }
}

// ---------------- GEMM2: 128x128 tile, BK=64, counted-vmcnt schedule ----------------
// out0[M=4096, N=1024] fp32 = ao[4096,1024] @ woutT[1024,1024]^T
// Grid 256 = 32m x 8n; per-XCD chunk = 4 m-panels x all n (A 1MB + B 2MB, L2-fit).
__global__ __launch_bounds__(256, 2) void k_gemm2(const u16* __restrict__ A,
                                                  const u16* __restrict__ Bt,
                                                  float* __restrict__ outf){
  __shared__ u16 As[2][8192];
  __shared__ u16 Bs[2][8192];
  const int K = 1024, KT = 16, N = 1024;

  int xcd = blockIdx.x & 7, c = blockIdx.x >> 3;       // c in 0..31
  int m0 = (xcd * 4 + (c >> 3)) << 7;
  int n0 = (c & 7) << 7;

  int t = threadIdx.x, wv = t >> 6, lane = t & 63, l15 = lane & 15, g = lane >> 4;
  int wm = wv >> 1, wn = wv & 1;

  auto STAGE = [&](int buf, int kt){
    int k0 = kt << 6;
#pragma unroll
    for (int i = 0; i < 4; i++){
      int cc = (i * 4 + wv) * 64 + lane;
      int m = cc >> 3, pos = cc & 7;
      GLL16(A + (size_t)(m0 + m) * K + k0 + ((pos ^ (m & 7)) << 3), &As[buf][(i * 4 + wv) * 512]);
    }
#pragma unroll
    for (int i = 0; i < 4; i++){
      int cc = (i * 4 + wv) * 64 + lane;
      int n = cc >> 3, pos = cc & 7;
      GLL16(Bt + (size_t)(n0 + n) * K + k0 + ((pos ^ (n & 7)) << 3), &Bs[buf][(i * 4 + wv) * 512]);
    }
  };

  f32x4 acc[4][4] = {};
  STAGE(0, 0);
  STAGE(1, 1);

  for (int kt = 0; kt < KT; kt++){
    if (kt < KT - 1) asm volatile("s_waitcnt vmcnt(8)" ::: "memory");
    else             asm volatile("s_waitcnt vmcnt(0)" ::: "memory");
    SCHEDB; BARRIER; SCHEDB;
    const u16* Asc = &As[kt & 1][0];
    const u16* Bsc = &Bs[kt & 1][0];
#pragma unroll
    for (int h = 0; h < 2; h++){
      short8 af[4], bfr[4];
#pragma unroll
      for (int mi = 0; mi < 4; mi++){
        int m = wm * 64 + mi * 16 + l15;
        af[mi] = *(const short8*)(Asc + m * 64 + (((h * 4 + g) ^ (m & 7)) << 3));
      }
#pragma unroll
      for (int ni = 0; ni < 4; ni++){
        int n = wn * 64 + ni * 16 + l15;
        bfr[ni] = *(const short8*)(Bsc + n * 64 + (((h * 4 + g) ^ (n & 7)) << 3));
      }
      __builtin_amdgcn_s_setprio(1);
#pragma unroll
      for (int mi = 0; mi < 4; mi++)
#pragma unroll
        for (int ni = 0; ni < 4; ni++)
          acc[mi][ni] = __builtin_amdgcn_mfma_f32_16x16x32_bf16(af[mi], bfr[ni], acc[mi][ni], 0, 0, 0);
      __builtin_amdgcn_s_setprio(0);
    }
    asm volatile("s_waitcnt lgkmcnt(0)" ::: "memory");
    SCHEDB; BARRIER; SCHEDB;
    if (kt + 2 < KT) STAGE(kt & 1, kt + 2);
  }

#pragma unroll
  for (int mi = 0; mi < 4; mi++){
#pragma unroll
    for (int ni = 0; ni < 4; ni++){
      int col = n0 + wn * 64 + ni * 16 + l15;
#pragma unroll
      for (int r = 0; r < 4; r++){
        int row = m0 + wm * 64 + mi * 16 + g * 4 + r;
        outf[(size_t)row * N + col] = acc[mi][ni][r];
      }
    }
  }
}

// ---------------- flash block-causal attention (unchanged from R8) ----------------
__global__ __launch_bounds__(512, 4) void k_attn(const u16* __restrict__ qkv2,
                                                 const u16* __restrict__ vt2,
                                                 u16* __restrict__ ao){
  __shared__ u16 Ks[2][8192];   // [kv=128][hd=64] per buf, XOR-swizzled chunks (32KB)
  __shared__ u16 Vs[8192];      // [d=64][kv=128], XOR-swizzled chunks (16KB)
  __shared__ u16 Ps[8][1024];   // per-wave P half [16q][64kv], swizzle ^((q&7)<<4) (16KB)

  int bid = blockIdx.x;
  int bh = bid & 31;                          // bid%8 stable -> same-bh on same XCD
  int idx = (bid >> 5) & 7;
  int half = bid >> 8;
  int qb = half ? idx : 15 - idx;
  int b = bh >> 4, h = bh & 15;
  int t = threadIdx.x, wv = t >> 6, lane = t & 63, l15 = lane & 15, g = lane >> 4;

  int qrow = qb * 128 + wv * 16 + l15;
  const u16* qp = qkv2 + (size_t)(b * N_ + qrow) * NQK_ + h * 64 + g * 8;
  short8 qfa = *(const short8*)qp;        // already roped + 1/8-scaled
  short8 qfb = *(const short8*)(qp + 32);

  char* Pw = (char*)&Ps[wv][0];
  const u16* vb_ = vt2 + (size_t)bh * 4096 * 32;   // vt2[bh][nc][d][32]

  auto STAGE_K = [&](int buf, int j) {
#pragma unroll
    for (int i = 0; i < 2; i++){
      int c = (i * 8 + wv) * 64 + lane;
      int kv = c >> 3, pos = c & 7;
      GLL16(qkv2 + (size_t)(b * N_ + j * 128 + kv) * NQK_ + DIM_ + h * 64 + ((pos ^ (kv & 7)) << 3),
            &Ks[buf][(i * 8 + wv) * 512]);
    }
  };
  auto STAGE_V = [&](int j) {
#pragma unroll
    for (int i = 0; i < 2; i++){
      int c = (wv * 2 + i) * 64 + lane;
      int d = c >> 4;
      int lc = (c & 15) ^ (d & 7);
      GLL16(vb_ + ((size_t)((j * 4 + (lc >> 2)) * 64 + d) * 32) + ((lc & 3) << 3),
            &Vs[(wv * 2 + i) * 512]);
    }
  };

  f32x4 oacc[4] = {};
  float m_run = -INFINITY, l_run = 0.0f;

  STAGE_K(0, 0);
  __syncthreads();
  int cur = 0;

  for (int j = 0; j <= qb; j++){
    STAGE_V(j);                                // issues 2 loads (oldest)
    if (j < qb) STAGE_K(cur ^ 1, j + 1);       // issues 2 more (newest)
    const u16* K = &Ks[cur][0];

    f32x4 sv[8];
    __builtin_amdgcn_s_setprio(1);
#pragma unroll
    for (int s = 0; s < 8; s++){
      int kvr = s * 16 + l15;
      short8 kf0 = *(const short8*)(K + kvr * 64 + ((g ^ (kvr & 7)) << 3));
      short8 kf1 = *(const short8*)(K + kvr * 64 + (((4 + g) ^ (kvr & 7)) << 3));
      f32x4 z = {0.f, 0.f, 0.f, 0.f};
      z = __builtin_amdgcn_mfma_f32_16x16x32_bf16(kf0, qfa, z, 0, 0, 0);
      z = __builtin_amdgcn_mfma_f32_16x16x32_bf16(kf1, qfb, z, 0, 0, 0);
      sv[s] = z;
    }
    __builtin_amdgcn_s_setprio(0);

    float mt = -INFINITY;
#pragma unroll
    for (int s = 0; s < 8; s++)
#pragma unroll
      for (int r = 0; r < 4; r++) mt = fmaxf(mt, sv[s][r]);
    mt = fmaxf(mt, __shfl_xor(mt, 16, 64));
    mt = fmaxf(mt, __shfl_xor(mt, 32, 64));
    if (!__all(mt <= m_run + 8.0f)){
      float m_new = fmaxf(m_run, mt);
      float alpha = exp2f((m_run - m_new) * 1.44269504f);
      float af4[4];
#pragma unroll
      for (int r = 0; r < 4; r++) af4[r] = __shfl(alpha, g * 4 + r, 64);
#pragma unroll
      for (int ni = 0; ni < 4; ni++)
#pragma unroll
        for (int r = 0; r < 4; r++) oacc[ni][r] *= af4[r];
      l_run *= alpha;
      m_run = m_new;
    }
    float psum = 0.0f;
#pragma unroll
    for (int s = 0; s < 8; s++)
#pragma unroll
      for (int r = 0; r < 4; r++){
        float p = exp2f((sv[s][r] - m_run) * 1.44269504f);
        sv[s][r] = p;
        psum += p;
      }
    psum += __shfl_xor(psum, 16, 64);
    psum += __shfl_xor(psum, 32, 64);
    l_run += psum;

    // V(j) landed (own oldest 2 loads); K(j+1) stays in flight through PV
    if (j < qb) asm volatile("s_waitcnt vmcnt(2)" ::: "memory");
    else        asm volatile("s_waitcnt vmcnt(0)" ::: "memory");
    SCHEDB; BARRIER; SCHEDB;

#pragma unroll
    for (int hf = 0; hf < 2; hf++){
#pragma unroll
      for (int s2 = 0; s2 < 4; s2++){
        int s = hf * 4 + s2;
        uint2 pk;
        pk.x = cvtpk(sv[s][0], sv[s][1]);
        pk.y = cvtpk(sv[s][2], sv[s][3]);
        int byte = (l15 * 128 + s2 * 32 + g * 8) ^ ((l15 & 7) << 4);
        *(uint2*)(Pw + byte) = pk;
      }
      __builtin_amdgcn_s_setprio(1);
#pragma unroll
      for (int cc2 = 0; cc2 < 2; cc2++){
        int cc = hf * 2 + cc2;
        int rb = (l15 * 128 + cc2 * 64 + g * 16) ^ ((l15 & 7) << 4);
        short8 pa = *(const short8*)(Pw + rb);
#pragma unroll
        for (int ni = 0; ni < 4; ni++){
          int d = ni * 16 + l15;
          short8 vf = *(const short8*)(Vs + d * 128 + (((cc * 4 + g) ^ (d & 7)) << 3));
          oacc[ni] = __builtin_amdgcn_mfma_f32_16x16x32_bf16(pa, vf, oacc[ni], 0, 0, 0);
        }
      }
      __builtin_amdgcn_s_setprio(0);
    }

    __syncthreads();   // all waves done with Vs / Ks[cur]; K(j+1) drained (flew full tile)
    cur ^= 1;
  }

  float lf[4];
#pragma unroll
  for (int r = 0; r < 4; r++) lf[r] = 1.0f / __shfl(l_run, g * 4 + r, 64);
#pragma unroll
  for (int ni = 0; ni < 4; ni++)
#pragma unroll
    for (int r = 0; r < 4; r++){
      size_t idxo = (size_t)(b * N_ + qb * 128 + wv * 16 + g * 4 + r) * DIM_ + h * 64 + ni * 16 + l15;
      ao[idxo] = f2bf(oacc[ni][r] * lf[r]);
    }
}

// ---------------- launch ----------------
extern "C" void kernel_launch(void* const* d_in, const int* in_sizes, int n_in,
                              void* d_out, int out_size, void* d_ws, size_t ws_size,
                              hipStream_t stream){
  const float* x      = (const float*)d_in[0];
  const float* norm_w = (const float*)d_in[1];
  const float* w_qkv  = (const float*)d_in[2];
  const float* w_out  = (const float*)d_in[3];
  float* out0 = (float*)d_out;                      // [B,N,DIM] fp32
  float* out1 = out0 + (size_t)NR_ * DIM_;          // orig_v [B,H,N,DH] fp32

  char* ws = (char*)d_ws;
  u16* xn    = (u16*)(ws + 0);           // 8 MB (reused as attn-out after GEMM1)
  u16* wqkvT = (u16*)(ws + 8388608);     // 6 MB
  u16* woutT = (u16*)(ws + 14680064);    // 2 MB
  u16* qkv2  = (u16*)(ws + 16777216);    // 16 MB  [row][2048] q|k bf16
  u16* vt2   = (u16*)(ws + 33554432);    // 8 MB   [bh][64][64][32] bf16
  float2* cs = (float2*)(ws + 41943040); // 0.5 MB
  u16* ao    = xn;                       // alias: xn dead after GEMM1

  k_rmsnorm<<<NR_, 256, 0, stream>>>(x, norm_w, xn);
  k_tcast<<<dim3(NQKV_ / 64, DIM_ / 64), 256, 0, stream>>>(w_qkv, wqkvT, DIM_, NQKV_);
  k_tcast<<<dim3(DIM_ / 64, DIM_ / 64), 256, 0, stream>>>(w_out, woutT, DIM_, DIM_);
  k_cs<<<(N_ * 32) / 256, 256, 0, stream>>>(cs);
  k_gemm1<<<512, 256, 0, stream>>>(xn, wqkvT, qkv2, out1, vt2);
  k_rope<<<4096, 256, 0, stream>>>(qkv2, cs);
  k_attn<<<512, 512, 0, stream>>>(qkv2, vt2, ao);
  k_gemm2<<<256, 256, 0, stream>>>(ao, woutT, out0);
}